// Round 16
// baseline (1489.330 us; speedup 1.0000x reference)
//
#include <hip/hip_runtime.h>

#define Bsz  256
#define Tlen 2048
#define Hdim 128
#define NTHR 1024

typedef __fp16 hf2 __attribute__((ext_vector_type(2)));

// Raw-HW transcendentals (VOP1, quarter-rate, ~1 ulp). R12-verified win.
__device__ __forceinline__ float fexp2_(float x) {
    float r; asm("v_exp_f32 %0, %1" : "=v"(r) : "v"(x)); return r;
}
__device__ __forceinline__ float frcp_(float x) {
    float r; asm("v_rcp_f32 %0, %1" : "=v"(r) : "v"(x)); return r;
}
__device__ __forceinline__ float sigmoidf_(float v) {
    return frcp_(1.0f + fexp2_(v * -1.44269504f));
}
__device__ __forceinline__ float tanhf_(float v) {
    return 1.0f - 2.0f * frcp_(fexp2_(v * 2.88539008f) + 1.0f);
}

// DPP butterfly add — pure VALU pipe.
template <int CTRL>
__device__ __forceinline__ float dpp_add(float v) {
    int t = __builtin_amdgcn_update_dpp(0, __float_as_int(v), CTRL, 0xf, 0xf, true);
    return v + __int_as_float(t);
}
// 8-lane allreduce: quad_perm xor1, xor2, row_half_mirror. R7/R10-verified.
__device__ __forceinline__ float red8(float v) {
    v = dpp_add<0xB1>(v);
    v = dpp_add<0x4E>(v);
    v = dpp_add<0x141>(v);
    return v;
}

// --- named packed-f16 weight strips (16 f32 -> 8 packed VGPRs each) ---
#define DECL8(p) hf2 p##0, p##1, p##2, p##3, p##4, p##5, p##6, p##7
#define LOAD8H(p, ptr) do {                                          \
    const float4* _q = (const float4*)(ptr);                         \
    float4 _a = _q[0], _b = _q[1], _c = _q[2], _d = _q[3];           \
    p##0 = __builtin_amdgcn_cvt_pkrtz(_a.x, _a.y);                   \
    p##1 = __builtin_amdgcn_cvt_pkrtz(_a.z, _a.w);                   \
    p##2 = __builtin_amdgcn_cvt_pkrtz(_b.x, _b.y);                   \
    p##3 = __builtin_amdgcn_cvt_pkrtz(_b.z, _b.w);                   \
    p##4 = __builtin_amdgcn_cvt_pkrtz(_c.x, _c.y);                   \
    p##5 = __builtin_amdgcn_cvt_pkrtz(_c.z, _c.w);                   \
    p##6 = __builtin_amdgcn_cvt_pkrtz(_d.x, _d.y);                   \
    p##7 = __builtin_amdgcn_cvt_pkrtz(_d.z, _d.w); } while (0)
// 8 chained v_dot2_f32_f16 against h0..h7
#define DOT8(acc, p) do {                                            \
    acc = __builtin_amdgcn_fdot2(p##0, h0, acc, false);              \
    acc = __builtin_amdgcn_fdot2(p##1, h1, acc, false);              \
    acc = __builtin_amdgcn_fdot2(p##2, h2, acc, false);              \
    acc = __builtin_amdgcn_fdot2(p##3, h3, acc, false);              \
    acc = __builtin_amdgcn_fdot2(p##4, h4, acc, false);              \
    acc = __builtin_amdgcn_fdot2(p##5, h5, acc, false);              \
    acc = __builtin_amdgcn_fdot2(p##6, h6, acc, false);              \
    acc = __builtin_amdgcn_fdot2(p##7, h7, acc, false); } while (0)

// grid = 256 blocks (one batch row per block), block = 1024 threads (16 waves,
// 4 waves/SIMD). R16: occupancy experiment — R15 (2 waves/SIMD) measured
// ~1400 cyc/step against ~600 cyc/SIMD of issue: stall-dominated. 4 waves/SIMD
// doubles latency hiding at the cost of ~960 cyc/SIMD issue (8-lane groups:
// 32 dot2 + red8 + full gate set per wave). This is R5's config with every
// since-discovered fix: f16 weights (32 VGPRs — fits the 128-VGPR budget,
// allocator fight moot), raw v_exp/v_rcp, LDS-staged outputs, R10 h-layout.
// thread t: kc = tid & 7 -> k-chunk [kc*16, kc*16+16); u = tid >> 3 (unit).
// h LDS: hf2[96] = 8 chunks x 12 hf2 (8 data + 4 pad); bases kc*48 B ->
// banks {0,12,24,4,16,28,8,20} distinct, conflict-free (R10-verified).
__global__ __launch_bounds__(NTHR)
void rnn_imp_kernel(const float* __restrict__ x,     // [B, T] (I=1)
                    const float* __restrict__ Wih,   // [384]
                    const float* __restrict__ Whh,   // [384, 128]
                    const float* __restrict__ bih,   // [384]
                    const float* __restrict__ bhh,   // [384]
                    const float* __restrict__ Wfc,   // [128]
                    const float* __restrict__ bfc,   // [1]
                    float* __restrict__ out_newin,   // [T, B]
                    float* __restrict__ out_pred)    // [B, T-1]
{
    __shared__ __align__(16) float x_s[Tlen + 4];
    __shared__ __align__(16) float xh_s[Tlen + 4];
    __shared__ __align__(16) hf2  h16_s[2][96];     // 8 chunks x (8 data + 4 pad)

    const int tid = threadIdx.x;
    const int b   = blockIdx.x;
    const int kc  = tid & 7;
    const int u   = tid >> 3;

    // stage x row (coalesced) and zero h buffer 0
    for (int i = tid; i < Tlen; i += NTHR) x_s[i] = x[b * Tlen + i];
    if (tid < 96) h16_s[0][tid] = hf2{(__fp16)0, (__fp16)0};

    // weight strips: rows {u, u+128, u+256} + Wfc over k in [kc*16, kc*16+16)
    DECL8(wr); DECL8(wz); DECL8(wn); DECL8(wf);
    LOAD8H(wr, Whh + (0 * Hdim + u) * Hdim + kc * 16);
    LOAD8H(wz, Whh + (1 * Hdim + u) * Hdim + kc * 16);
    LOAD8H(wn, Whh + (2 * Hdim + u) * Hdim + kc * 16);
    LOAD8H(wf, Wfc + kc * 16);

    // per-unit gate constants (identical across the 8 lanes of a group)
    const float wih_r = Wih[u], wih_z = Wih[u + 128], wih_n = Wih[u + 256];
    const float bb_r = bih[u]       + bhh[u];
    const float bb_z = bih[u + 128] + bhh[u + 128];
    const float bi_n = bih[u + 256];
    const float bh_n = bhh[u + 256];
    const float bfc0 = bfc[0];
    float h_old = 0.0f;

    const int rbase = kc * 12;                          // hf2 chunk base
    const int pu    = (u >> 4) * 24 + (u & 15);         // __fp16 write index

    __syncthreads();

#pragma unroll 1
    for (int t = 0; t < Tlen; ++t) {
        const hf2* hb = h16_s[t & 1];
        __fp16*    hw = (__fp16*)h16_s[(t + 1) & 1];
        float xt = x_s[t];

        // h chunk: 2x ds_read_b128 of packed f16 (16 values)
        const float4* hp = (const float4*)(hb + rbase);
        float4 qa = hp[0], qb = hp[1];
        hf2 h0 = __builtin_bit_cast(hf2, qa.x), h1 = __builtin_bit_cast(hf2, qa.y),
            h2 = __builtin_bit_cast(hf2, qa.z), h3 = __builtin_bit_cast(hf2, qa.w),
            h4 = __builtin_bit_cast(hf2, qb.x), h5 = __builtin_bit_cast(hf2, qb.y),
            h6 = __builtin_bit_cast(hf2, qb.z), h7 = __builtin_bit_cast(hf2, qb.w);

        float ar = 0.f, az = 0.f, an = 0.f, axp = 0.f;
        DOT8(axp, wf);                  // xp first: xh feeds the gate chain
        DOT8(ar, wr);
        DOT8(az, wz);
        DOT8(an, wn);

        // 8-lane allreduce; every lane of the group holds the full sums
        float xp = red8(axp);
        float gr = red8(ar);
        float gz = red8(az);
        float gn = red8(an);

        float xh  = xp + bfc0;
        float cur = ((xt == 128.0f) && (t != 0)) ? xh : xt;

        float r  = sigmoidf_(wih_r * cur + bb_r + gr);
        float z  = sigmoidf_(wih_z * cur + bb_z + gz);
        float n  = tanhf_(wih_n * cur + bi_n + r * (gn + bh_n));
        float hn = (1.0f - z) * n + z * h_old;
        h_old = hn;

        if (kc == 0) hw[pu] = (__fp16)hn;   // ds_write_b16, 2-way alias = free
        if (tid == 0) xh_s[t] = xh;         // LDS staging (R14-verified)
        __syncthreads();
    }

    // bulk flush: cur reconstructed from pristine x_s + xh_s (no in-loop store)
    for (int i = tid; i < Tlen; i += NTHR) {
        float xv = x_s[i];
        float cv = ((xv == 128.0f) && (i != 0)) ? xh_s[i] : xv;
        out_newin[i * Bsz + b] = cv;
    }
    for (int i = tid; i < Tlen - 1; i += NTHR)
        out_pred[b * (Tlen - 1) + i] = xh_s[i + 1];
}

extern "C" void kernel_launch(void* const* d_in, const int* in_sizes, int n_in,
                              void* d_out, int out_size, void* d_ws, size_t ws_size,
                              hipStream_t stream) {
    const float* x   = (const float*)d_in[0];
    const float* Wih = (const float*)d_in[1];
    const float* Whh = (const float*)d_in[2];
    const float* bih = (const float*)d_in[3];
    const float* bhh = (const float*)d_in[4];
    const float* Wfc = (const float*)d_in[5];
    const float* bfc = (const float*)d_in[6];

    float* out_newin = (float*)d_out;                 // [T*B] = 524288
    float* out_pred  = out_newin + Tlen * Bsz;        // [B*(T-1)] = 524032

    rnn_imp_kernel<<<Bsz, NTHR, 0, stream>>>(x, Wih, Whh, bih, bhh, Wfc, bfc,
                                             out_newin, out_pred);
}

// Round 17
// 1169.988 us; speedup vs baseline: 1.2729x; 1.2729x over previous
//
#include <hip/hip_runtime.h>

#define Bsz  256
#define Tlen 2048
#define Hdim 128

typedef __fp16 hf2 __attribute__((ext_vector_type(2)));

// Raw-HW transcendentals (VOP1, quarter-rate, ~1 ulp). R12-verified win.
__device__ __forceinline__ float fexp2_(float x) {
    float r; asm("v_exp_f32 %0, %1" : "=v"(r) : "v"(x)); return r;
}
__device__ __forceinline__ float frcp_(float x) {
    float r; asm("v_rcp_f32 %0, %1" : "=v"(r) : "v"(x)); return r;
}
__device__ __forceinline__ float sigmoidf_(float v) {
    return frcp_(1.0f + fexp2_(v * -1.44269504f));
}
__device__ __forceinline__ float tanhf_(float v) {
    return 1.0f - 2.0f * frcp_(fexp2_(v * 2.88539008f) + 1.0f);
}

// DPP butterfly add — pure VALU pipe.
template <int CTRL>
__device__ __forceinline__ float dpp_add(float v) {
    int t = __builtin_amdgcn_update_dpp(0, __float_as_int(v), CTRL, 0xf, 0xf, true);
    return v + __int_as_float(t);
}
// 4-lane allreduce within a quad (R15-verified).
__device__ __forceinline__ float red4(float v) {
    v = dpp_add<0xB1>(v);   // quad_perm xor1
    v = dpp_add<0x4E>(v);   // quad_perm xor2
    return v;
}

__device__ __forceinline__ hf2 bch(float f) { return __builtin_bit_cast(hf2, f); }

// --- weight strips via VOLATILE loads ---------------------------------------
// R17's single change. Volatile loads may not be duplicated or sunk into the
// t-loop (it would change the access count), so the converted f16 values are
// FORCED live across all 2048 iterations. This is the residency mechanism that
// pins (R4/R13), named scalars (R7), AGPR constraints (R8), and dtype shrink
// (R10) all failed to achieve: VGPR_Count sat at 56-88 — below the weight
// footprint — with ~90 mystery re-load/cvt instrs per wave per step.
#define DECL8(p) hf2 p##0, p##1, p##2, p##3, p##4, p##5, p##6, p##7
#define LOAD8HV(p, ptr) do {                                         \
    volatile const float* _q = (volatile const float*)(ptr);         \
    float _f0 = _q[0],  _f1 = _q[1],  _f2 = _q[2],  _f3 = _q[3];     \
    float _f4 = _q[4],  _f5 = _q[5],  _f6 = _q[6],  _f7 = _q[7];     \
    float _f8 = _q[8],  _f9 = _q[9],  _fa = _q[10], _fb = _q[11];    \
    float _fc = _q[12], _fd = _q[13], _fe = _q[14], _ff = _q[15];    \
    p##0 = __builtin_amdgcn_cvt_pkrtz(_f0, _f1);                     \
    p##1 = __builtin_amdgcn_cvt_pkrtz(_f2, _f3);                     \
    p##2 = __builtin_amdgcn_cvt_pkrtz(_f4, _f5);                     \
    p##3 = __builtin_amdgcn_cvt_pkrtz(_f6, _f7);                     \
    p##4 = __builtin_amdgcn_cvt_pkrtz(_f8, _f9);                     \
    p##5 = __builtin_amdgcn_cvt_pkrtz(_fa, _fb);                     \
    p##6 = __builtin_amdgcn_cvt_pkrtz(_fc, _fd);                     \
    p##7 = __builtin_amdgcn_cvt_pkrtz(_fe, _ff); } while (0)
// chained v_dot2_f32_f16 against h0..h7 / h8..h15
#define DOT8L(acc, p) do {                                           \
    acc = __builtin_amdgcn_fdot2(p##0, h0, acc, false);              \
    acc = __builtin_amdgcn_fdot2(p##1, h1, acc, false);              \
    acc = __builtin_amdgcn_fdot2(p##2, h2, acc, false);              \
    acc = __builtin_amdgcn_fdot2(p##3, h3, acc, false);              \
    acc = __builtin_amdgcn_fdot2(p##4, h4, acc, false);              \
    acc = __builtin_amdgcn_fdot2(p##5, h5, acc, false);              \
    acc = __builtin_amdgcn_fdot2(p##6, h6, acc, false);              \
    acc = __builtin_amdgcn_fdot2(p##7, h7, acc, false); } while (0)
#define DOT8H(acc, p) do {                                           \
    acc = __builtin_amdgcn_fdot2(p##0, h8,  acc, false);             \
    acc = __builtin_amdgcn_fdot2(p##1, h9,  acc, false);             \
    acc = __builtin_amdgcn_fdot2(p##2, h10, acc, false);             \
    acc = __builtin_amdgcn_fdot2(p##3, h11, acc, false);             \
    acc = __builtin_amdgcn_fdot2(p##4, h12, acc, false);             \
    acc = __builtin_amdgcn_fdot2(p##5, h13, acc, false);             \
    acc = __builtin_amdgcn_fdot2(p##6, h14, acc, false);             \
    acc = __builtin_amdgcn_fdot2(p##7, h15, acc, false); } while (0)

// grid = 256 blocks (one batch row per block), block = 512 threads (8 waves).
// R15 mapping (best: 1196 us): kc = tid & 3 (32 k-values), u = tid >> 2.
// h in LDS as raw f16: chunk kc at 80 B stride (banks 0,20,8,28) conflict-free.
__global__ __launch_bounds__(512, 2)
void rnn_imp_kernel(const float* __restrict__ x,     // [B, T] (I=1)
                    const float* __restrict__ Wih,   // [384]
                    const float* __restrict__ Whh,   // [384, 128]
                    const float* __restrict__ bih,   // [384]
                    const float* __restrict__ bhh,   // [384]
                    const float* __restrict__ Wfc,   // [128]
                    const float* __restrict__ bfc,   // [1]
                    float* __restrict__ out_newin,   // [T, B]
                    float* __restrict__ out_pred)    // [B, T-1]
{
    __shared__ __align__(16) float  x_s[Tlen + 4];
    __shared__ __align__(16) float  xh_s[Tlen + 4];
    __shared__ __align__(16) __fp16 hbuf[2][160];   // 4 chunks x (64 data + 16B pad)

    const int tid = threadIdx.x;
    const int b   = blockIdx.x;
    const int kc  = tid & 3;
    const int u   = tid >> 2;

    // stage x row (coalesced) and zero h buffer 0
    for (int i = tid; i < Tlen; i += 512) x_s[i] = x[b * Tlen + i];
    if (tid < 160) hbuf[0][tid] = (__fp16)0.0f;

    // weight strips: rows {u, u+128, u+256} + Wfc over k in [kc*32, kc*32+32)
    DECL8(rl); DECL8(rh); DECL8(zl); DECL8(zh);
    DECL8(nl); DECL8(nh); DECL8(fl); DECL8(fh);
    const int kb = kc * 32;
    LOAD8HV(rl, Whh + (0 * Hdim + u) * Hdim + kb);
    LOAD8HV(rh, Whh + (0 * Hdim + u) * Hdim + kb + 16);
    LOAD8HV(zl, Whh + (1 * Hdim + u) * Hdim + kb);
    LOAD8HV(zh, Whh + (1 * Hdim + u) * Hdim + kb + 16);
    LOAD8HV(nl, Whh + (2 * Hdim + u) * Hdim + kb);
    LOAD8HV(nh, Whh + (2 * Hdim + u) * Hdim + kb + 16);
    LOAD8HV(fl, Wfc + kb);
    LOAD8HV(fh, Wfc + kb + 16);

    // per-unit gate constants (identical across the 4 lanes of a quad)
    const float wih_r = Wih[u], wih_z = Wih[u + 128], wih_n = Wih[u + 256];
    const float bb_r = bih[u]       + bhh[u];
    const float bb_z = bih[u + 128] + bhh[u + 128];
    const float bi_n = bih[u + 256];
    const float bh_n = bhh[u + 256];
    const float bfc0 = bfc[0];
    float h_old = 0.0f;

    const int rb = kc * 40;                 // f16 chunk base (80 B stride)
    const int pu = u + (u >> 5) * 8;        // padded f16 write index

    __syncthreads();

#pragma unroll 1
    for (int t = 0; t < Tlen; ++t) {
        const __fp16* hb = hbuf[t & 1];
        __fp16*       hw = hbuf[(t + 1) & 1];
        float xt = x_s[t];

        // h chunk: 4x ds_read_b128 (32 packed f16 values)
        const float4* hp = (const float4*)(hb + rb);
        float4 qa = hp[0], qb = hp[1], qc = hp[2], qd = hp[3];
        hf2 h0  = bch(qa.x), h1  = bch(qa.y), h2  = bch(qa.z), h3  = bch(qa.w),
            h4  = bch(qb.x), h5  = bch(qb.y), h6  = bch(qb.z), h7  = bch(qb.w),
            h8  = bch(qc.x), h9  = bch(qc.y), h10 = bch(qc.z), h11 = bch(qc.w),
            h12 = bch(qd.x), h13 = bch(qd.y), h14 = bch(qd.z), h15 = bch(qd.w);

        float ar = 0.f, az = 0.f, an = 0.f, axp = 0.f;
        DOT8L(axp, fl); DOT8H(axp, fh);     // xp first: xh feeds the chain
        DOT8L(ar,  rl); DOT8H(ar,  rh);
        DOT8L(az,  zl); DOT8H(az,  zh);
        DOT8L(an,  nl); DOT8H(an,  nh);

        // 4-lane quad allreduce; every lane of the quad holds the full sums
        float xp = red4(axp);
        float gr = red4(ar);
        float gz = red4(az);
        float gn = red4(an);

        float xh  = xp + bfc0;
        float cur = ((xt == 128.0f) && (t != 0)) ? xh : xt;

        float r  = sigmoidf_(wih_r * cur + bb_r + gr);
        float z  = sigmoidf_(wih_z * cur + bb_z + gz);
        float n  = tanhf_(wih_n * cur + bi_n + r * (gn + bh_n));
        float hn = (1.0f - z) * n + z * h_old;
        h_old = hn;

        if (kc == 0) hw[pu] = (__fp16)hn;   // ds_write_b16, 2-way alias = free
        if (tid == 0) {
            x_s[t]  = cur;                  // LDS staging (R14-verified)
            xh_s[t] = xh;
        }
        __syncthreads();
    }

    // bulk flush: one vmcnt drain total instead of one per step
    for (int i = tid; i < Tlen; i += 512)
        out_newin[i * Bsz + b] = x_s[i];
    for (int i = tid; i < Tlen - 1; i += 512)
        out_pred[b * (Tlen - 1) + i] = xh_s[i + 1];
}

extern "C" void kernel_launch(void* const* d_in, const int* in_sizes, int n_in,
                              void* d_out, int out_size, void* d_ws, size_t ws_size,
                              hipStream_t stream) {
    const float* x   = (const float*)d_in[0];
    const float* Wih = (const float*)d_in[1];
    const float* Whh = (const float*)d_in[2];
    const float* bih = (const float*)d_in[3];
    const float* bhh = (const float*)d_in[4];
    const float* Wfc = (const float*)d_in[5];
    const float* bfc = (const float*)d_in[6];

    float* out_newin = (float*)d_out;                 // [T*B] = 524288
    float* out_pred  = out_newin + Tlen * Bsz;        // [B*(T-1)] = 524032

    rnn_imp_kernel<<<Bsz, 512, 0, stream>>>(x, Wih, Whh, bih, bhh, Wfc, bfc,
                                            out_newin, out_pred);
}